// Round 2
// baseline (665.069 us; speedup 1.0000x reference)
//
#include <hip/hip_runtime.h>

#define SEQK 512
#define NH 16
#define HD 64
#define RD 1024
#define BBATCH 32
#define MTOT (BBATCH * SEQK)   // 16384
#define QK_SCALE 0.125f        // 1/sqrt(64)

typedef unsigned short u16;
using bf16x8 = __attribute__((ext_vector_type(8))) short;
using f32x4  = __attribute__((ext_vector_type(4))) float;

__device__ __forceinline__ u16 f2bf(float f) {
  unsigned u = __float_as_uint(f);
  u += 0x7FFFu + ((u >> 16) & 1u);   // round-to-nearest-even
  return (u16)(u >> 16);
}

__device__ __forceinline__ void async_cp16(const void* g, void* l) {
  __builtin_amdgcn_global_load_lds(
      (__attribute__((address_space(1))) void*)(void*)g,
      (__attribute__((address_space(3))) void*)l,
      16, 0, 0);
}

// ---------------------------------------------------------------- convert
__global__ void convert_kernel(const float* __restrict__ hR,
                               const float* __restrict__ Wq, const float* __restrict__ Wk,
                               const float* __restrict__ Wv, const float* __restrict__ Wo,
                               u16* __restrict__ hR16,
                               u16* __restrict__ Wq16, u16* __restrict__ Wk16,
                               u16* __restrict__ Wv16, u16* __restrict__ Wo16) {
  size_t i4 = (size_t)blockIdx.x * blockDim.x + threadIdx.x;
  size_t e = i4 * 4;
  const float* src; u16* dst; size_t off;
  if (e < 16777216u) { src = hR; dst = hR16; off = e; }
  else {
    size_t r = e - 16777216u;
    int w = (int)(r >> 20);
    off = r & 1048575u;
    src = (w == 0 ? Wq : w == 1 ? Wk : w == 2 ? Wv : Wo);
    dst = (w == 0 ? Wq16 : w == 1 ? Wk16 : w == 2 ? Wv16 : Wo16);
  }
  float4 v = *(const float4*)(src + off);
  ushort4 o;
  o.x = f2bf(v.x); o.y = f2bf(v.y); o.z = f2bf(v.z); o.w = f2bf(v.w);
  *(ushort4*)(dst + off) = o;
}

// ---------------------------------------------------------------- R normalize
__global__ void rnorm_kernel(const float* __restrict__ R, float* __restrict__ Rn) {
  int row = blockIdx.x;
  int lane = threadIdx.x;
  float4 v = *(const float4*)(R + (size_t)row * 256 + lane * 4);
  float ss = v.x * v.x + v.y * v.y + v.z * v.z + v.w * v.w;
  for (int off = 32; off; off >>= 1) ss += __shfl_xor(ss, off);
  float s = 1.0f / fmaxf(sqrtf(ss), 1e-12f);
  float4 o = {v.x * s, v.y * s, v.z * s, v.w * s};
  *(float4*)(Rn + (size_t)row * 256 + lane * 4) = o;
}

// ---------------------------------------------------------------- sim = Rn @ Rn^T
__global__ void sim_kernel(const float* __restrict__ Rn, float* __restrict__ sim) {
  __shared__ float Rl[16 * 256];
  int i0 = blockIdx.x * 16;
  int t = threadIdx.x;
  #pragma unroll
  for (int i = 0; i < 4; i++) {
    int f = t + i * 256;
    *(float4*)&Rl[f * 4] = *(const float4*)(Rn + (size_t)i0 * 256 + f * 4);
  }
  __syncthreads();
  for (int jj = 0; jj < 2; jj++) {
    int j = jj * 256 + t;
    float acc[16];
    #pragma unroll
    for (int i = 0; i < 16; i++) acc[i] = 0.f;
    for (int c = 0; c < 64; c++) {
      float4 rv = *(const float4*)(Rn + (size_t)j * 256 + c * 4);
      #pragma unroll
      for (int i = 0; i < 16; i++) {
        float4 a = *(const float4*)&Rl[i * 256 + c * 4];
        acc[i] += a.x * rv.x + a.y * rv.y + a.z * rv.z + a.w * rv.w;
      }
    }
    #pragma unroll
    for (int i = 0; i < 16; i++) sim[(size_t)(i0 + i) * 512 + j] = acc[i];
  }
}

// ---------------------------------------------------------------- GEMM (bf16 MFMA)
template <int MODE>
__global__ __launch_bounds__(256)
void gemm_kernel(const u16* __restrict__ A,
                 const u16* __restrict__ B0, const u16* __restrict__ B1,
                 const u16* __restrict__ B2,
                 u16* __restrict__ q16, u16* __restrict__ k16, u16* __restrict__ v16,
                 float* __restrict__ outF) {
  __shared__ u16 Alds[128 * 32];
  __shared__ u16 Blds[128 * 32];
  int tid = threadIdx.x;
  int wave = tid >> 6, lane = tid & 63;
  int wm = wave & 1, wn = wave >> 1;
  int lr = lane & 15, qd = lane >> 4;
  int mb = blockIdx.x * 128;
  int ny = blockIdx.y;

  const u16* Bmat;
  int nbmat;
  if (MODE == 0) {
    int wsel = ny >> 3;
    Bmat = (wsel == 0 ? B0 : wsel == 1 ? B1 : B2);
    nbmat = (ny & 7) * 128;
  } else {
    Bmat = B0;
    nbmat = ny * 128;
  }

  f32x4 zero = {0.f, 0.f, 0.f, 0.f};
  f32x4 acc[4][4];
  #pragma unroll
  for (int i = 0; i < 4; i++)
    #pragma unroll
    for (int j = 0; j < 4; j++) acc[i][j] = zero;

  for (int kb = 0; kb < 1024; kb += 32) {
    #pragma unroll
    for (int j = 0; j < 2; j++) {
      int r = (wave * 2 + j) * 16 + (lane >> 2);
      int c = (lane & 3) ^ ((r >> 1) & 3);
      async_cp16(A + (size_t)(mb + r) * 1024 + kb + c * 8,
                 &Alds[(wave * 2 + j) * 512]);
      async_cp16(Bmat + (size_t)(nbmat + r) * 1024 + kb + c * 8,
                 &Blds[(wave * 2 + j) * 512]);
    }
    __syncthreads();

    bf16x8 af[4], bf[4];
    #pragma unroll
    for (int mi = 0; mi < 4; mi++) {
      int ra = wm * 64 + mi * 16 + lr;
      af[mi] = *(const bf16x8*)&Alds[ra * 32 + ((qd ^ ((ra >> 1) & 3)) << 3)];
      int rb = wn * 64 + mi * 16 + lr;
      bf[mi] = *(const bf16x8*)&Blds[rb * 32 + ((qd ^ ((rb >> 1) & 3)) << 3)];
    }
    #pragma unroll
    for (int mi = 0; mi < 4; mi++)
      #pragma unroll
      for (int ni = 0; ni < 4; ni++)
        acc[mi][ni] = __builtin_amdgcn_mfma_f32_16x16x32_bf16(af[mi], bf[ni],
                                                              acc[mi][ni], 0, 0, 0);
    __syncthreads();
  }

  if (MODE == 0) {
    int wsel = ny >> 3;
    u16* dst = (wsel == 0 ? q16 : wsel == 1 ? k16 : v16);
    float scl = (wsel == 0) ? QK_SCALE : 1.0f;
    #pragma unroll
    for (int mi = 0; mi < 4; mi++) {
      int m = mb + wm * 64 + mi * 16 + qd * 4;
      int b = m >> 9, kk = m & 511;
      #pragma unroll
      for (int ni = 0; ni < 4; ni++) {
        int n = nbmat + wn * 64 + ni * 16 + lr;
        int h = n >> 6, d = n & 63;
        u16* p = dst + ((size_t)(b * 16 + h) * 512 + kk) * 64 + d;
        #pragma unroll
        for (int r = 0; r < 4; r++) p[(size_t)r * 64] = f2bf(acc[mi][ni][r] * scl);
      }
    }
  } else {
    #pragma unroll
    for (int mi = 0; mi < 4; mi++) {
      int m = mb + wm * 64 + mi * 16 + qd * 4;
      #pragma unroll
      for (int ni = 0; ni < 4; ni++) {
        int n = ny * 128 + wn * 64 + ni * 16 + lr;
        #pragma unroll
        for (int r = 0; r < 4; r++) outF[(size_t)(m + r) * 1024 + n] = acc[mi][ni][r];
      }
    }
  }
}

// ---------------------------------------------------------------- V transpose
__global__ void vtrans_kernel(const u16* __restrict__ v16, u16* __restrict__ vt16) {
  __shared__ u16 tile[64 * 72];
  int kt = blockIdx.x;
  int bh = blockIdx.y;
  int t = threadIdx.x;
  const u16* src = v16 + ((size_t)bh * 512 + kt * 64) * 64;
  #pragma unroll
  for (int j = 0; j < 2; j++) {
    int linear = j * 2048 + t * 8;
    int kr = linear >> 6, d0 = linear & 63;
    bf16x8 vv = *(const bf16x8*)(src + (size_t)kr * 64 + d0);
    #pragma unroll
    for (int e = 0; e < 8; e++) tile[kr * 72 + d0 + e] = (u16)vv[e];
  }
  __syncthreads();
  #pragma unroll
  for (int j = 0; j < 2; j++) {
    int linear = j * 2048 + t * 8;
    int dr = linear >> 6, k0 = linear & 63;
    bf16x8 ov;
    #pragma unroll
    for (int e = 0; e < 8; e++) ov[e] = (short)tile[(k0 + e) * 72 + dr];
    *(bf16x8*)(vt16 + ((size_t)bh * 64 + dr) * 512 + kt * 64 + k0) = ov;
  }
}

// ---------------------------------------------------------------- fused attention
// Online-softmax flash style. One block per (qt, h, b), decoded with an
// XCD-swizzle: blocks sharing (b,h) land on ONE xcd as temporally-adjacent
// slots -> K/V stay in that XCD's L2 (FETCH 282->~120 MB).
// 4 waves; wave w owns q rows [qt*64+w*16, +16). K processed in 4 chunks of
// 128: chunk S = 8 f32x4 acc (32 regs, was 128), bias folded into MFMA C-init
// via symmetric sim float4 loads. P goes through a per-wave XOR-swizzled LDS
// region (16 KB total, NO __syncthreads — each wave reads only its own rows).
__global__ __launch_bounds__(256, 4)
void attn_kernel(const u16* __restrict__ q16, const u16* __restrict__ k16,
                 const u16* __restrict__ vt16, const float* __restrict__ sim,
                 const float* __restrict__ wsim, u16* __restrict__ attn16) {
  __shared__ u16 Plds[4 * 16 * 128];   // 16 KB, per-wave 16x128 region
  int id = blockIdx.x;
  int xcd = id & 7;
  int j = id >> 3;            // 0..511
  int qt = j & 7;             // adjacent slots on one xcd share (b,h)
  int bh = xcd * 64 + (j >> 3);
  int b = bh >> 4, h = bh & 15;

  int tid = threadIdx.x;
  int wave = tid >> 6, lane = tid & 63;
  int lr = lane & 15, qd = lane >> 4;
  int qrb = qt * 64 + wave * 16;
  u16* Pw = &Plds[wave * 2048];

  const u16* qp = q16 + ((size_t)bh * 512 + qrb + lr) * 64 + qd * 8;
  bf16x8 aq0 = *(const bf16x8*)qp;
  bf16x8 aq1 = *(const bf16x8*)(qp + 32);

  float ws = wsim[h];
  int row0 = qrb + qd * 4;    // q row for reg r: row0 + r

  f32x4 zero = {0.f, 0.f, 0.f, 0.f};
  f32x4 o[4];
  #pragma unroll
  for (int nt = 0; nt < 4; nt++) o[nt] = zero;
  float m_run[4] = {-1e30f, -1e30f, -1e30f, -1e30f};
  float l_run[4] = {0.f, 0.f, 0.f, 0.f};

  const u16* kbase = k16 + (size_t)bh * 512 * 64;
  const u16* vbase = vt16 + (size_t)bh * 64 * 512;

  for (int ck = 0; ck < 4; ck++) {
    int k0 = ck * 128;
    // ---- QK^T for chunk, bias as C-init (sim symmetric: read [k][q] as float4)
    f32x4 s[8];
    #pragma unroll
    for (int jt = 0; jt < 8; jt++) {
      int kpos = k0 + jt * 16 + lr;
      float4 b4 = *(const float4*)(sim + (size_t)kpos * 512 + row0);
      f32x4 t = {ws * b4.x, ws * b4.y, ws * b4.z, ws * b4.w};
      const u16* kp = kbase + (size_t)kpos * 64 + qd * 8;
      t = __builtin_amdgcn_mfma_f32_16x16x32_bf16(aq0, *(const bf16x8*)kp, t, 0, 0, 0);
      t = __builtin_amdgcn_mfma_f32_16x16x32_bf16(aq1, *(const bf16x8*)(kp + 32), t, 0, 0, 0);
      s[jt] = t;
    }
    // ---- online softmax update
    float mnew[4], alpha[4], csum[4];
    #pragma unroll
    for (int r = 0; r < 4; r++) {
      float m = s[0][r];
      #pragma unroll
      for (int jt = 1; jt < 8; jt++) m = fmaxf(m, s[jt][r]);
      m = fmaxf(m, __shfl_xor(m, 1));
      m = fmaxf(m, __shfl_xor(m, 2));
      m = fmaxf(m, __shfl_xor(m, 4));
      m = fmaxf(m, __shfl_xor(m, 8));
      mnew[r] = fmaxf(m_run[r], m);
      alpha[r] = __expf(m_run[r] - mnew[r]);
      m_run[r] = mnew[r];
      csum[r] = 0.f;
    }
    #pragma unroll
    for (int jt = 0; jt < 8; jt++)
      #pragma unroll
      for (int r = 0; r < 4; r++) {
        float e = __expf(s[jt][r] - mnew[r]);
        s[jt][r] = e;
        csum[r] += e;
      }
    #pragma unroll
    for (int r = 0; r < 4; r++) {
      float t = csum[r];
      t += __shfl_xor(t, 1); t += __shfl_xor(t, 2);
      t += __shfl_xor(t, 4); t += __shfl_xor(t, 8);
      l_run[r] = l_run[r] * alpha[r] + t;
    }
    // ---- P -> LDS (XOR chunk swizzle: logical (row,k) at row*128 + ((k>>3)^row)*8 + (k&7))
    #pragma unroll
    for (int jt = 0; jt < 8; jt++) {
      int c = jt * 2 + (lr >> 3);
      int e = lr & 7;
      #pragma unroll
      for (int r = 0; r < 4; r++) {
        int row = qd * 4 + r;
        Pw[row * 128 + ((c ^ row) & 15) * 8 + e] = f2bf(s[jt][r]);
      }
    }
    // ---- rescale O, then PV for chunk (per-wave LDS region: no barrier needed)
    #pragma unroll
    for (int nt = 0; nt < 4; nt++)
      #pragma unroll
      for (int r = 0; r < 4; r++) o[nt][r] *= alpha[r];
    #pragma unroll
    for (int ks = 0; ks < 4; ks++) {
      bf16x8 ap = *(const bf16x8*)&Pw[lr * 128 + (((ks * 4 + qd) ^ lr) & 15) * 8];
      #pragma unroll
      for (int nt = 0; nt < 4; nt++) {
        const u16* vp = vbase + (size_t)(nt * 16 + lr) * 512 + k0 + ks * 32 + qd * 8;
        o[nt] = __builtin_amdgcn_mfma_f32_16x16x32_bf16(ap, *(const bf16x8*)vp, o[nt], 0, 0, 0);
      }
    }
  }

  float inv[4];
  #pragma unroll
  for (int r = 0; r < 4; r++) inv[r] = 1.0f / l_run[r];
  #pragma unroll
  for (int nt = 0; nt < 4; nt++)
    #pragma unroll
    for (int r = 0; r < 4; r++) {
      float val = o[nt][r] * inv[r];
      attn16[((size_t)b * 512 + row0 + r) * 1024 + h * 64 + nt * 16 + lr] = f2bf(val);
    }
}

// ---------------------------------------------------------------- launch
extern "C" void kernel_launch(void* const* d_in, const int* in_sizes, int n_in,
                              void* d_out, int out_size, void* d_ws, size_t ws_size,
                              hipStream_t stream) {
  const float* hR  = (const float*)d_in[0];
  const float* R   = (const float*)d_in[1];
  const float* Wq  = (const float*)d_in[2];
  const float* Wk  = (const float*)d_in[3];
  const float* Wv  = (const float*)d_in[4];
  const float* Wo  = (const float*)d_in[5];
  const float* wsm = (const float*)d_in[6];
  float* out = (float*)d_out;

  const size_t NE = 16777216;   // 16384 x 1024
  u16* ws16   = (u16*)d_ws;
  u16* hR16   = ws16;
  u16* attn16 = ws16;           // reuses hR16 (consumed by QKV GEMM)
  u16* q16    = ws16 + NE;
  u16* k16    = ws16 + 2 * NE;
  u16* v16    = ws16 + 3 * NE;
  u16* vt16   = ws16 + 4 * NE;
  u16* Wq16   = ws16 + 5 * NE;
  u16* Wk16   = Wq16 + 1048576;
  u16* Wv16   = Wk16 + 1048576;
  u16* Wo16   = Wv16 + 1048576;
  float* Rn   = (float*)(Wo16 + 1048576);
  float* sim  = Rn + 512 * 256;

  convert_kernel<<<20480, 256, 0, stream>>>(hR, Wq, Wk, Wv, Wo,
                                            hR16, Wq16, Wk16, Wv16, Wo16);
  rnorm_kernel<<<512, 64, 0, stream>>>(R, Rn);
  sim_kernel<<<32, 256, 0, stream>>>(Rn, sim);
  gemm_kernel<0><<<dim3(128, 24), 256, 0, stream>>>(hR16, Wq16, Wk16, Wv16,
                                                    q16, k16, v16, nullptr);
  vtrans_kernel<<<dim3(8, 512), 256, 0, stream>>>(v16, vt16);
  attn_kernel<<<4096, 256, 0, stream>>>(q16, k16, vt16, sim, wsm, attn16);
  gemm_kernel<1><<<dim3(128, 8), 256, 0, stream>>>(attn16, Wo16, nullptr, nullptr,
                                                   nullptr, nullptr, nullptr, out);
}

// Round 3
// 494.596 us; speedup vs baseline: 1.3447x; 1.3447x over previous
//
#include <hip/hip_runtime.h>

#define SEQK 512
#define NH 16
#define HD 64
#define RD 1024
#define BBATCH 32
#define QK_SCALE 0.125f        // 1/sqrt(64)

typedef unsigned short u16;
using bf16x8 = __attribute__((ext_vector_type(8))) short;
using f32x4  = __attribute__((ext_vector_type(4))) float;

__device__ __forceinline__ u16 f2bf(float f) {
  unsigned u = __float_as_uint(f);
  u += 0x7FFFu + ((u >> 16) & 1u);   // round-to-nearest-even
  return (u16)(u >> 16);
}
__device__ __forceinline__ float bf2f(u16 v) {
  return __uint_as_float(((unsigned)v) << 16);
}

__device__ __forceinline__ void async_cp16(const void* g, void* l) {
  __builtin_amdgcn_global_load_lds(
      (__attribute__((address_space(1))) void*)(void*)g,
      (__attribute__((address_space(3))) void*)l,
      16, 0, 0);
}

// ---------------------------------------------------------------- convert
__global__ void convert_kernel(const float* __restrict__ hR,
                               const float* __restrict__ Wq, const float* __restrict__ Wk,
                               const float* __restrict__ Wv, const float* __restrict__ Wo,
                               u16* __restrict__ hR16,
                               u16* __restrict__ Wq16, u16* __restrict__ Wk16,
                               u16* __restrict__ Wv16, u16* __restrict__ Wo16) {
  size_t i4 = (size_t)blockIdx.x * blockDim.x + threadIdx.x;
  size_t e = i4 * 4;
  const float* src; u16* dst; size_t off;
  if (e < 16777216u) { src = hR; dst = hR16; off = e; }
  else {
    size_t r = e - 16777216u;
    int w = (int)(r >> 20);
    off = r & 1048575u;
    src = (w == 0 ? Wq : w == 1 ? Wk : w == 2 ? Wv : Wo);
    dst = (w == 0 ? Wq16 : w == 1 ? Wk16 : w == 2 ? Wv16 : Wo16);
  }
  float4 v = *(const float4*)(src + off);
  ushort4 o;
  o.x = f2bf(v.x); o.y = f2bf(v.y); o.z = f2bf(v.z); o.w = f2bf(v.w);
  *(ushort4*)(dst + off) = o;
}

// ---------------------------------------------------------------- R normalize
__global__ void rnorm_kernel(const float* __restrict__ R, float* __restrict__ Rn) {
  int row = blockIdx.x;
  int lane = threadIdx.x;
  float4 v = *(const float4*)(R + (size_t)row * 256 + lane * 4);
  float ss = v.x * v.x + v.y * v.y + v.z * v.z + v.w * v.w;
  for (int off = 32; off; off >>= 1) ss += __shfl_xor(ss, off);
  float s = 1.0f / fmaxf(sqrtf(ss), 1e-12f);
  float4 o = {v.x * s, v.y * s, v.z * s, v.w * s};
  *(float4*)(Rn + (size_t)row * 256 + lane * 4) = o;
}

// ---------------------------------------------------------------- sim = Rn @ Rn^T  (bf16 out)
__global__ void sim_kernel(const float* __restrict__ Rn, u16* __restrict__ sim16) {
  __shared__ float Rl[16 * 256];
  int i0 = blockIdx.x * 16;
  int t = threadIdx.x;
  #pragma unroll
  for (int i = 0; i < 4; i++) {
    int f = t + i * 256;
    *(float4*)&Rl[f * 4] = *(const float4*)(Rn + (size_t)i0 * 256 + f * 4);
  }
  __syncthreads();
  for (int jj = 0; jj < 2; jj++) {
    int j = jj * 256 + t;
    float acc[16];
    #pragma unroll
    for (int i = 0; i < 16; i++) acc[i] = 0.f;
    for (int c = 0; c < 64; c++) {
      float4 rv = *(const float4*)(Rn + (size_t)j * 256 + c * 4);
      #pragma unroll
      for (int i = 0; i < 16; i++) {
        float4 a = *(const float4*)&Rl[i * 256 + c * 4];
        acc[i] += a.x * rv.x + a.y * rv.y + a.z * rv.z + a.w * rv.w;
      }
    }
    #pragma unroll
    for (int i = 0; i < 16; i++) sim16[(size_t)(i0 + i) * 512 + j] = f2bf(acc[i]);
  }
}

// ---------------------------------------------------------------- GEMM (bf16 MFMA)
template <int MODE>
__global__ __launch_bounds__(256)
void gemm_kernel(const u16* __restrict__ A,
                 const u16* __restrict__ B0, const u16* __restrict__ B1,
                 const u16* __restrict__ B2,
                 u16* __restrict__ q16, u16* __restrict__ k16, u16* __restrict__ v16,
                 float* __restrict__ outF) {
  __shared__ u16 Alds[128 * 32];
  __shared__ u16 Blds[128 * 32];
  int tid = threadIdx.x;
  int wave = tid >> 6, lane = tid & 63;
  int wm = wave & 1, wn = wave >> 1;
  int lr = lane & 15, qd = lane >> 4;
  int mb = blockIdx.x * 128;
  int ny = blockIdx.y;

  const u16* Bmat;
  int nbmat;
  if (MODE == 0) {
    int wsel = ny >> 3;
    Bmat = (wsel == 0 ? B0 : wsel == 1 ? B1 : B2);
    nbmat = (ny & 7) * 128;
  } else {
    Bmat = B0;
    nbmat = ny * 128;
  }

  f32x4 zero = {0.f, 0.f, 0.f, 0.f};
  f32x4 acc[4][4];
  #pragma unroll
  for (int i = 0; i < 4; i++)
    #pragma unroll
    for (int j = 0; j < 4; j++) acc[i][j] = zero;

  for (int kb = 0; kb < 1024; kb += 32) {
    #pragma unroll
    for (int j = 0; j < 2; j++) {
      int r = (wave * 2 + j) * 16 + (lane >> 2);
      int c = (lane & 3) ^ ((r >> 1) & 3);
      async_cp16(A + (size_t)(mb + r) * 1024 + kb + c * 8,
                 &Alds[(wave * 2 + j) * 512]);
      async_cp16(Bmat + (size_t)(nbmat + r) * 1024 + kb + c * 8,
                 &Blds[(wave * 2 + j) * 512]);
    }
    __syncthreads();

    bf16x8 af[4], bf[4];
    #pragma unroll
    for (int mi = 0; mi < 4; mi++) {
      int ra = wm * 64 + mi * 16 + lr;
      af[mi] = *(const bf16x8*)&Alds[ra * 32 + ((qd ^ ((ra >> 1) & 3)) << 3)];
      int rb = wn * 64 + mi * 16 + lr;
      bf[mi] = *(const bf16x8*)&Blds[rb * 32 + ((qd ^ ((rb >> 1) & 3)) << 3)];
    }
    #pragma unroll
    for (int mi = 0; mi < 4; mi++)
      #pragma unroll
      for (int ni = 0; ni < 4; ni++)
        acc[mi][ni] = __builtin_amdgcn_mfma_f32_16x16x32_bf16(af[mi], bf[ni],
                                                              acc[mi][ni], 0, 0, 0);
    __syncthreads();
  }

  if (MODE == 0) {
    int wsel = ny >> 3;
    u16* dst = (wsel == 0 ? q16 : wsel == 1 ? k16 : v16);
    float scl = (wsel == 0) ? QK_SCALE : 1.0f;
    #pragma unroll
    for (int mi = 0; mi < 4; mi++) {
      int m = mb + wm * 64 + mi * 16 + qd * 4;
      int b = m >> 9, kk = m & 511;
      #pragma unroll
      for (int ni = 0; ni < 4; ni++) {
        int n = nbmat + wn * 64 + ni * 16 + lr;
        int h = n >> 6, d = n & 63;
        u16* p = dst + ((size_t)(b * 16 + h) * 512 + kk) * 64 + d;
        #pragma unroll
        for (int r = 0; r < 4; r++) p[(size_t)r * 64] = f2bf(acc[mi][ni][r] * scl);
      }
    }
  } else {
    #pragma unroll
    for (int mi = 0; mi < 4; mi++) {
      int m = mb + wm * 64 + mi * 16 + qd * 4;
      #pragma unroll
      for (int ni = 0; ni < 4; ni++) {
        int n = ny * 128 + wn * 64 + ni * 16 + lr;
        #pragma unroll
        for (int r = 0; r < 4; r++) outF[(size_t)(m + r) * 1024 + n] = acc[mi][ni][r];
      }
    }
  }
}

// ---------------------------------------------------------------- V transpose
__global__ void vtrans_kernel(const u16* __restrict__ v16, u16* __restrict__ vt16) {
  __shared__ u16 tile[64 * 72];
  int kt = blockIdx.x;
  int bh = blockIdx.y;
  int t = threadIdx.x;
  const u16* src = v16 + ((size_t)bh * 512 + kt * 64) * 64;
  #pragma unroll
  for (int j = 0; j < 2; j++) {
    int linear = j * 2048 + t * 8;
    int kr = linear >> 6, d0 = linear & 63;
    bf16x8 vv = *(const bf16x8*)(src + (size_t)kr * 64 + d0);
    #pragma unroll
    for (int e = 0; e < 8; e++) tile[kr * 72 + d0 + e] = (u16)vv[e];
  }
  __syncthreads();
  #pragma unroll
  for (int j = 0; j < 2; j++) {
    int linear = j * 2048 + t * 8;
    int dr = linear >> 6, k0 = linear & 63;
    bf16x8 ov;
    #pragma unroll
    for (int e = 0; e < 8; e++) ov[e] = (short)tile[(k0 + e) * 72 + dr];
    *(bf16x8*)(vt16 + ((size_t)bh * 64 + dr) * 512 + kt * 64 + k0) = ov;
  }
}

// ---------------------------------------------------------------- fused attention v3
// Flash (online softmax), K-chunk=128. K and V chunks are staged ONCE PER
// BLOCK into LDS via global_load_lds(16B) with a baked-in XOR chunk swizzle
// (reads hit the 8-clk ds_read_b128 floor) — kills the R1 bottleneck of
// every wave gathering K/V from L2 with 16-line-touch VMEM instrs (4x
// instr count + 4x L2 traffic). Bias is bf16 (sim16), loaded directly.
// XCD-swizzled grid: the 8 blocks sharing (b,h) are temporally adjacent on
// one XCD. LDS 48KB -> 3 blocks/CU.
__global__ __launch_bounds__(256, 3)
void attn_kernel(const u16* __restrict__ q16, const u16* __restrict__ k16,
                 const u16* __restrict__ vt16, const u16* __restrict__ sim16,
                 const float* __restrict__ wsim, u16* __restrict__ attn16) {
  __shared__ u16 Kbuf[128 * 64];    // [kl][d], 16B chunks of each row XOR-swizzled by kl&7
  __shared__ u16 Vbuf[64 * 128];    // [d][kl], 16B chunks of each row XOR-swizzled by d&15
  __shared__ u16 Plds[4 * 16 * 128];

  int id = blockIdx.x;
  int xcd = id & 7;
  int j = id >> 3;
  int qt = j & 7;
  int bh = xcd * 64 + (j >> 3);
  int b = bh >> 4, h = bh & 15;

  int tid = threadIdx.x;
  int wave = tid >> 6, lane = tid & 63;
  int lr = lane & 15, qd = lane >> 4;
  int qrb = qt * 64 + wave * 16;
  u16* Pw = &Plds[wave * 2048];

  const u16* qp = q16 + ((size_t)bh * 512 + qrb + lr) * 64 + qd * 8;
  bf16x8 aq0 = *(const bf16x8*)qp;
  bf16x8 aq1 = *(const bf16x8*)(qp + 32);

  float ws = wsim[h];
  int row0 = qrb + qd * 4;

  f32x4 zero = {0.f, 0.f, 0.f, 0.f};
  f32x4 o[4];
  #pragma unroll
  for (int nt = 0; nt < 4; nt++) o[nt] = zero;
  float m_run[4] = {-1e30f, -1e30f, -1e30f, -1e30f};
  float l_run[4] = {0.f, 0.f, 0.f, 0.f};

  const u16* kbase = k16 + (size_t)bh * 512 * 64;
  const u16* vbase = vt16 + (size_t)bh * 64 * 512;

  for (int ck = 0; ck < 4; ck++) {
    int k0 = ck * 128;
    __syncthreads();   // previous chunk's LDS reads done before overwrite
    // ---- stage K chunk: rows kl 0..127 x 64 d (128B rows), swizzled 16B chunks
    #pragma unroll
    for (int jj = 0; jj < 4; jj++) {
      int rbase = wave * 32 + jj * 8;
      int r = rbase + (lane >> 3);
      int c = (lane & 7) ^ (r & 7);
      async_cp16(kbase + (size_t)(k0 + r) * 64 + c * 8, &Kbuf[rbase * 64]);
    }
    // ---- stage V chunk: rows d 0..63 x 128 k (256B rows), swizzled 16B chunks
    #pragma unroll
    for (int jj = 0; jj < 4; jj++) {
      int dbase = wave * 16 + jj * 4;
      int d = dbase + (lane >> 4);
      int c = (lane & 15) ^ (d & 15);
      async_cp16(vbase + (size_t)d * 512 + k0 + c * 8, &Vbuf[dbase * 128]);
    }
    __syncthreads();   // drain async, data visible to all waves

    // ---- QK^T, bias (bf16 global) as C-init
    f32x4 s[8];
    #pragma unroll
    for (int jt = 0; jt < 8; jt++) {
      int kl = jt * 16 + lr;
      ushort4 b4 = *(const ushort4*)(sim16 + (size_t)(k0 + kl) * 512 + row0);
      f32x4 t = {ws * bf2f(b4.x), ws * bf2f(b4.y), ws * bf2f(b4.z), ws * bf2f(b4.w)};
      const u16* krow = &Kbuf[kl * 64];
      int sw = kl & 7;
      bf16x8 kf0 = *(const bf16x8*)(krow + ((qd ^ sw) << 3));
      bf16x8 kf1 = *(const bf16x8*)(krow + (((qd + 4) ^ sw) << 3));
      t = __builtin_amdgcn_mfma_f32_16x16x32_bf16(aq0, kf0, t, 0, 0, 0);
      t = __builtin_amdgcn_mfma_f32_16x16x32_bf16(aq1, kf1, t, 0, 0, 0);
      s[jt] = t;
    }
    // ---- online softmax update
    float mnew[4], alpha[4], csum[4];
    #pragma unroll
    for (int r = 0; r < 4; r++) {
      float m = s[0][r];
      #pragma unroll
      for (int jt = 1; jt < 8; jt++) m = fmaxf(m, s[jt][r]);
      m = fmaxf(m, __shfl_xor(m, 1));
      m = fmaxf(m, __shfl_xor(m, 2));
      m = fmaxf(m, __shfl_xor(m, 4));
      m = fmaxf(m, __shfl_xor(m, 8));
      mnew[r] = fmaxf(m_run[r], m);
      alpha[r] = __expf(m_run[r] - mnew[r]);
      m_run[r] = mnew[r];
      csum[r] = 0.f;
    }
    #pragma unroll
    for (int jt = 0; jt < 8; jt++)
      #pragma unroll
      for (int r = 0; r < 4; r++) {
        float e = __expf(s[jt][r] - mnew[r]);
        s[jt][r] = e;
        csum[r] += e;
      }
    #pragma unroll
    for (int r = 0; r < 4; r++) {
      float t = csum[r];
      t += __shfl_xor(t, 1); t += __shfl_xor(t, 2);
      t += __shfl_xor(t, 4); t += __shfl_xor(t, 8);
      l_run[r] = l_run[r] * alpha[r] + t;
    }
    // ---- P -> per-wave LDS (XOR chunk swizzle), no barrier
    #pragma unroll
    for (int jt = 0; jt < 8; jt++) {
      int c = jt * 2 + (lr >> 3);
      int e = lr & 7;
      #pragma unroll
      for (int r = 0; r < 4; r++) {
        int row = qd * 4 + r;
        Pw[row * 128 + ((c ^ row) & 15) * 8 + e] = f2bf(s[jt][r]);
      }
    }
    // ---- rescale O, PV from LDS
    #pragma unroll
    for (int nt = 0; nt < 4; nt++)
      #pragma unroll
      for (int r = 0; r < 4; r++) o[nt][r] *= alpha[r];
    #pragma unroll
    for (int ks = 0; ks < 4; ks++) {
      bf16x8 ap = *(const bf16x8*)&Pw[lr * 128 + (((ks * 4 + qd) ^ lr) & 15) * 8];
      #pragma unroll
      for (int nt = 0; nt < 4; nt++) {
        int d = nt * 16 + lr;
        bf16x8 vf = *(const bf16x8*)&Vbuf[d * 128 + (((ks * 4 + qd) ^ (d & 15)) << 3)];
        o[nt] = __builtin_amdgcn_mfma_f32_16x16x32_bf16(ap, vf, o[nt], 0, 0, 0);
      }
    }
  }

  // ---- epilogue: normalize, transpose via per-wave LDS, coalesced 16B stores
  float inv[4];
  #pragma unroll
  for (int r = 0; r < 4; r++) inv[r] = 1.0f / l_run[r];
  u16* Ow = Pw;   // reuse per-wave region: [16 rows][64 d] stride 72
  #pragma unroll
  for (int nt = 0; nt < 4; nt++)
    #pragma unroll
    for (int r = 0; r < 4; r++)
      Ow[(qd * 4 + r) * 72 + nt * 16 + lr] = f2bf(o[nt][r] * inv[r]);
  #pragma unroll
  for (int it = 0; it < 2; it++) {
    int row = it * 8 + (lane >> 3);
    int seg = lane & 7;
    bf16x8 val = *(const bf16x8*)&Ow[row * 72 + seg * 8];
    *(bf16x8*)(attn16 + ((size_t)b * 512 + qrb + row) * 1024 + h * 64 + seg * 8) = val;
  }
}

// ---------------------------------------------------------------- launch
extern "C" void kernel_launch(void* const* d_in, const int* in_sizes, int n_in,
                              void* d_out, int out_size, void* d_ws, size_t ws_size,
                              hipStream_t stream) {
  const float* hR  = (const float*)d_in[0];
  const float* R   = (const float*)d_in[1];
  const float* Wq  = (const float*)d_in[2];
  const float* Wk  = (const float*)d_in[3];
  const float* Wv  = (const float*)d_in[4];
  const float* Wo  = (const float*)d_in[5];
  const float* wsm = (const float*)d_in[6];
  float* out = (float*)d_out;

  const size_t NE = 16777216;   // 16384 x 1024
  u16* ws16   = (u16*)d_ws;
  u16* hR16   = ws16;
  u16* attn16 = ws16;           // reuses hR16 (consumed by QKV GEMM)
  u16* q16    = ws16 + NE;
  u16* k16    = ws16 + 2 * NE;
  u16* v16    = ws16 + 3 * NE;
  u16* vt16   = ws16 + 4 * NE;
  u16* Wq16   = ws16 + 5 * NE;
  u16* Wk16   = Wq16 + 1048576;
  u16* Wv16   = Wk16 + 1048576;
  u16* Wo16   = Wv16 + 1048576;
  u16* sim16  = Wo16 + 1048576;              // 512*512 bf16
  float* Rn   = (float*)(sim16 + 262144);    // 512*256 fp32

  convert_kernel<<<20480, 256, 0, stream>>>(hR, Wq, Wk, Wv, Wo,
                                            hR16, Wq16, Wk16, Wv16, Wo16);
  rnorm_kernel<<<512, 64, 0, stream>>>(R, Rn);
  sim_kernel<<<32, 256, 0, stream>>>(Rn, sim16);
  gemm_kernel<0><<<dim3(128, 24), 256, 0, stream>>>(hR16, Wq16, Wk16, Wv16,
                                                    q16, k16, v16, nullptr);
  vtrans_kernel<<<dim3(8, 512), 256, 0, stream>>>(v16, vt16);
  attn_kernel<<<4096, 256, 0, stream>>>(q16, k16, vt16, sim16, wsm, attn16);
  gemm_kernel<1><<<dim3(128, 8), 256, 0, stream>>>(attn16, Wo16, nullptr, nullptr,
                                                   nullptr, nullptr, nullptr, out);
}